// Round 1
// baseline (674.426 us; speedup 1.0000x reference)
//
#include <hip/hip_runtime.h>
#include <math.h>

#define BB   8
#define CIN  64
#define COUT 64
#define HH   128
#define WW   128
#define HW   (HH*WW)
#define NPIX (BB*HW)

// ---------------------------------------------------------------------------
// K1: offset conv — 18 out channels, 3x3, pad 1, + b_off. One 16x16 pixel
// tile per block; x tile staged in LDS per input channel; weights staged
// once as [c][tap][oc(pad 20)] so inner reads are float4 LDS broadcasts.
// ---------------------------------------------------------------------------
__global__ __launch_bounds__(256) void k_offconv(
    const float* __restrict__ x, const float* __restrict__ w_off,
    const float* __restrict__ b_off, float* __restrict__ off)
{
  __shared__ float wl[CIN*9*20];   // 46080 B
  __shared__ float tile[18*18];
  const int tid = threadIdx.x;
  for (int i = tid; i < CIN*9*18; i += 256) {
    int c = i / 162, r = i % 162;
    int t = r / 18, oc = r % 18;
    wl[(c*9 + t)*20 + oc] = w_off[(oc*CIN + c)*9 + t];
  }
  const int blk = blockIdx.x;
  const int b = blk >> 6;               // 64 tiles per image
  const int tile_id = blk & 63;
  const int h0 = (tile_id >> 3) << 4;
  const int w0 = (tile_id & 7) << 4;
  const int ty = tid >> 4, tx = tid & 15;
  float acc[18];
#pragma unroll
  for (int i = 0; i < 18; ++i) acc[i] = 0.f;
  const float* xb = x + (size_t)b*CIN*HW;
  for (int c = 0; c < CIN; ++c) {
    const float* xc = xb + c*HW;
    __syncthreads();                    // protect tile/wl from prior reads
    for (int i = tid; i < 18*18; i += 256) {
      int r = i / 18, q = i % 18;
      int gy = h0 - 1 + r, gx = w0 - 1 + q;
      tile[i] = (gy >= 0 && gy < HH && gx >= 0 && gx < WW) ? xc[gy*WW + gx] : 0.f;
    }
    __syncthreads();
#pragma unroll
    for (int t = 0; t < 9; ++t) {
      float xv = tile[(ty + t/3)*18 + (tx + t%3)];
      const float* wt = &wl[(c*9 + t)*20];
      float4 a0 = *(const float4*)(wt + 0);
      float4 a1 = *(const float4*)(wt + 4);
      float4 a2 = *(const float4*)(wt + 8);
      float4 a3 = *(const float4*)(wt + 12);
      float2 a4 = *(const float2*)(wt + 16);
      acc[0]  = fmaf(xv, a0.x, acc[0]);
      acc[1]  = fmaf(xv, a0.y, acc[1]);
      acc[2]  = fmaf(xv, a0.z, acc[2]);
      acc[3]  = fmaf(xv, a0.w, acc[3]);
      acc[4]  = fmaf(xv, a1.x, acc[4]);
      acc[5]  = fmaf(xv, a1.y, acc[5]);
      acc[6]  = fmaf(xv, a1.z, acc[6]);
      acc[7]  = fmaf(xv, a1.w, acc[7]);
      acc[8]  = fmaf(xv, a2.x, acc[8]);
      acc[9]  = fmaf(xv, a2.y, acc[9]);
      acc[10] = fmaf(xv, a2.z, acc[10]);
      acc[11] = fmaf(xv, a2.w, acc[11]);
      acc[12] = fmaf(xv, a3.x, acc[12]);
      acc[13] = fmaf(xv, a3.y, acc[13]);
      acc[14] = fmaf(xv, a3.z, acc[14]);
      acc[15] = fmaf(xv, a3.w, acc[15]);
      acc[16] = fmaf(xv, a4.x, acc[16]);
      acc[17] = fmaf(xv, a4.y, acc[17]);
    }
  }
  const int p = (h0 + ty)*WW + (w0 + tx);
  float* ob = off + (size_t)b*18*HW + p;
#pragma unroll
  for (int oc = 0; oc < 18; ++oc) ob[oc*HW] = acc[oc] + b_off[oc];
}

// ---------------------------------------------------------------------------
// K2: transpose w_def (o,c,k) -> wT[k][c][o] (o contiguous for GEMM phase)
// ---------------------------------------------------------------------------
__global__ void k_transpose(const float* __restrict__ w_def, float* __restrict__ wT)
{
  const int i = blockIdx.x*256 + threadIdx.x;
  if (i >= COUT*CIN*9) return;
  const int k = i / (CIN*COUT);
  const int c = (i / COUT) % CIN;
  const int o = i % COUT;
  wT[i] = w_def[(o*CIN + c)*9 + k];
}

// ---------------------------------------------------------------------------
// K3: fused bilinear sample + deform einsum (+ bias, pre-BN store, BN stats).
// Block = 64 consecutive pixels (one row segment) x all 64 out channels.
// Phase 1: 4 waves sample 16 channels each -> S[c][p] in LDS.
// Phase 2: lane = (po,oo); 4x4 outer-product micro-tile from LDS.
// ---------------------------------------------------------------------------
__global__ __launch_bounds__(256) void k_deform(
    const float* __restrict__ x, const float* __restrict__ off,
    const float* __restrict__ wT, const float* __restrict__ b_def,
    float* __restrict__ pre, float* __restrict__ stats)
{
  __shared__ float S[CIN*64];    // 16 KB  [c][p]
  __shared__ float Wl[CIN*COUT]; // 16 KB  [c][o]
  const int tid = threadIdx.x;
  const int pix0 = blockIdx.x << 6;
  const int b = pix0 >> 14;
  const int img = pix0 & (HW - 1);
  const int h = img >> 7;
  const int wbase = img & (WW - 1);
  const int p = tid & 63, cg = tid >> 6;   // phase-1 mapping
  const int po = tid & 15, oo = tid >> 4;  // phase-2 mapping
  float acc[16];
#pragma unroll
  for (int i = 0; i < 16; ++i) acc[i] = 0.f;
  const float* xb = x + (size_t)b*CIN*HW;
  const int w = wbase + p;

  for (int k = 0; k < 9; ++k) {
    __syncthreads();                       // S/Wl free to overwrite
    {
      const float4* wsrc = (const float4*)(wT + k*CIN*COUT);
      float4* wdst = (float4*)Wl;
#pragma unroll
      for (int j = 0; j < 4; ++j) wdst[j*256 + tid] = wsrc[j*256 + tid];
    }
    const int kh = k / 3, kw = k % 3;
    const int ioff = (b*18 + 2*k)*HW + h*WW + w;
    const float dy = off[ioff];
    const float dx = off[ioff + HW];
    const float ys = (float)(h - 1 + kh) + dy;
    const float xs = (float)(w - 1 + kw) + dx;
    const float y0f = floorf(ys), x0f = floorf(xs);
    const float tyf = ys - y0f, txf = xs - x0f;
    const float wy0 = 1.f - tyf, wx0 = 1.f - txf;
    float w00 = wy0*wx0, w01 = wy0*txf, w10 = tyf*wx0, w11 = tyf*txf;
    const bool vy0 = (y0f >=  0.f) && (y0f <= 127.f);
    const bool vy1 = (y0f >= -1.f) && (y0f <= 126.f);
    const bool vx0 = (x0f >=  0.f) && (x0f <= 127.f);
    const bool vx1 = (x0f >= -1.f) && (x0f <= 126.f);
    w00 = (vy0 && vx0) ? w00 : 0.f;
    w01 = (vy0 && vx1) ? w01 : 0.f;
    w10 = (vy1 && vx0) ? w10 : 0.f;
    w11 = (vy1 && vx1) ? w11 : 0.f;
    const int yi0 = (int)fminf(fmaxf(y0f,       0.f), 127.f);
    const int yi1 = (int)fminf(fmaxf(y0f + 1.f, 0.f), 127.f);
    const int xi0 = (int)fminf(fmaxf(x0f,       0.f), 127.f);
    const int xi1 = (int)fminf(fmaxf(x0f + 1.f, 0.f), 127.f);
    const int o00 = yi0*WW + xi0, o01 = yi0*WW + xi1;
    const int o10 = yi1*WW + xi0, o11 = yi1*WW + xi1;
    const float* xc = xb + cg*16*HW;
    float* srow = &S[(cg*16)*64 + p];
#pragma unroll
    for (int ci = 0; ci < 16; ++ci) {
      float v = w00*xc[o00] + w01*xc[o01] + w10*xc[o10] + w11*xc[o11];
      srow[ci*64] = v;
      xc += HW;
    }
    __syncthreads();
#pragma unroll 8
    for (int c = 0; c < CIN; ++c) {
      float4 sp = *(const float4*)&S[c*64 + (po << 2)];
      float4 wt = *(const float4*)&Wl[c*64 + (oo << 2)];
      acc[0]  = fmaf(sp.x, wt.x, acc[0]);
      acc[1]  = fmaf(sp.x, wt.y, acc[1]);
      acc[2]  = fmaf(sp.x, wt.z, acc[2]);
      acc[3]  = fmaf(sp.x, wt.w, acc[3]);
      acc[4]  = fmaf(sp.y, wt.x, acc[4]);
      acc[5]  = fmaf(sp.y, wt.y, acc[5]);
      acc[6]  = fmaf(sp.y, wt.z, acc[6]);
      acc[7]  = fmaf(sp.y, wt.w, acc[7]);
      acc[8]  = fmaf(sp.z, wt.x, acc[8]);
      acc[9]  = fmaf(sp.z, wt.y, acc[9]);
      acc[10] = fmaf(sp.z, wt.z, acc[10]);
      acc[11] = fmaf(sp.z, wt.w, acc[11]);
      acc[12] = fmaf(sp.w, wt.x, acc[12]);
      acc[13] = fmaf(sp.w, wt.y, acc[13]);
      acc[14] = fmaf(sp.w, wt.z, acc[14]);
      acc[15] = fmaf(sp.w, wt.w, acc[15]);
    }
  }
  // epilogue: bias, pre-BN store (float4 per output channel), partial stats
  float s1[4], s2[4];
#pragma unroll
  for (int j = 0; j < 4; ++j) {
    const int o = oo*4 + j;
    const float bd = b_def[o];
    float4 v;
    v.x = acc[0*4+j] + bd;
    v.y = acc[1*4+j] + bd;
    v.z = acc[2*4+j] + bd;
    v.w = acc[3*4+j] + bd;
    *(float4*)&pre[((size_t)b*COUT + o)*HW + img + (po << 2)] = v;
    s1[j] = (v.x + v.y) + (v.z + v.w);
    s2[j] = (v.x*v.x + v.y*v.y) + (v.z*v.z + v.w*v.w);
  }
#pragma unroll
  for (int d = 8; d >= 1; d >>= 1) {
#pragma unroll
    for (int j = 0; j < 4; ++j) {
      s1[j] += __shfl_down(s1[j], d, 16);
      s2[j] += __shfl_down(s2[j], d, 16);
    }
  }
  if (po == 0) {
#pragma unroll
    for (int j = 0; j < 4; ++j) {
      atomicAdd(&stats[(oo*4 + j)*2 + 0], s1[j]);
      atomicAdd(&stats[(oo*4 + j)*2 + 1], s2[j]);
    }
  }
}

// ---------------------------------------------------------------------------
// K4: BN finalize (mean/var from stats) + gamma/beta + ReLU, float4-wide
// ---------------------------------------------------------------------------
__global__ __launch_bounds__(256) void k_bn(
    const float* __restrict__ pre, const float* __restrict__ stats,
    const float* __restrict__ gamma, const float* __restrict__ beta,
    float* __restrict__ out)
{
  const int i = blockIdx.x*256 + threadIdx.x;     // float4 index
  const int o = (i >> 12) & 63;                   // (i*4 / 16384) % 64
  const float inv_n = 1.f / (float)(BB*HW);
  const float mean = stats[2*o] * inv_n;
  const float var  = stats[2*o + 1] * inv_n - mean*mean;
  const float sc = rsqrtf(var + 1e-5f) * gamma[o];
  const float sh = fmaf(-mean, sc, beta[o]);
  float4 v = ((const float4*)pre)[i];
  v.x = fmaxf(fmaf(v.x, sc, sh), 0.f);
  v.y = fmaxf(fmaf(v.y, sc, sh), 0.f);
  v.z = fmaxf(fmaf(v.z, sc, sh), 0.f);
  v.w = fmaxf(fmaf(v.w, sc, sh), 0.f);
  ((float4*)out)[i] = v;
}

extern "C" void kernel_launch(void* const* d_in, const int* in_sizes, int n_in,
                              void* d_out, int out_size, void* d_ws, size_t ws_size,
                              hipStream_t stream)
{
  const float* x     = (const float*)d_in[0];
  const float* w_off = (const float*)d_in[1];
  const float* b_off = (const float*)d_in[2];
  const float* w_def = (const float*)d_in[3];
  const float* b_def = (const float*)d_in[4];
  const float* gamma = (const float*)d_in[5];
  const float* beta  = (const float*)d_in[6];
  float* out = (float*)d_out;

  float* off   = (float*)d_ws;                       // 8*18*16384
  float* wT    = off + (size_t)BB*18*HW;             // 9*64*64
  float* pre   = wT + (size_t)COUT*CIN*9;            // 8*64*16384
  float* stats = pre + (size_t)BB*COUT*HW;           // 128

  hipMemsetAsync(stats, 0, 128*sizeof(float), stream);
  hipLaunchKernelGGL(k_transpose, dim3(144), dim3(256), 0, stream, w_def, wT);
  hipLaunchKernelGGL(k_offconv, dim3(512), dim3(256), 0, stream, x, w_off, b_off, off);
  hipLaunchKernelGGL(k_deform, dim3(NPIX/64), dim3(256), 0, stream, x, off, wT, b_def, pre, stats);
  hipLaunchKernelGGL(k_bn, dim3(8192), dim3(256), 0, stream, pre, stats, gamma, beta, out);
}